// Round 2
// baseline (4412.958 us; speedup 1.0000x reference)
//
#include <hip/hip_runtime.h>

#define TT 2048

typedef _Float16 f16;
typedef _Float16 f16x2 __attribute__((ext_vector_type(2)));
typedef unsigned int u32;

static __device__ __forceinline__ float fdot2f(u32 a, u32 b, float c) {
#if __has_builtin(__builtin_amdgcn_fdot2)
  return __builtin_amdgcn_fdot2(__builtin_bit_cast(f16x2, a),
                                __builtin_bit_cast(f16x2, b), c, false);
#else
  f16x2 av = __builtin_bit_cast(f16x2, a);
  f16x2 bv = __builtin_bit_cast(f16x2, b);
  return c + (float)av[0]*(float)bv[0] + (float)av[1]*(float)bv[1];
#endif
}

static __device__ __forceinline__ u32 packh2(float a, float b) {
  f16x2 v; v[0] = (f16)a; v[1] = (f16)b;
  return __builtin_bit_cast(u32, v);
}

static __device__ __forceinline__ float sigm(float x) {
  return 1.f / (1.f + __expf(-x));
}
static __device__ __forceinline__ float tanh_(float x) {
  x = fminf(15.f, fmaxf(-15.f, x));
  const float e = __expf(2.f*x);
  return (e - 1.f) / (e + 1.f);
}

// One wave (64 lanes) == one batch row. Lane u owns layer-1 unit u
// (gates u, u+64, u+128, u+192) -> cell update is lane-local, NO barriers.
// Layer-2: lane l computes gates l and l+64; one shfl_xor(32) pair
// assembles (i,f,g,o) per unit. Weights live in VGPRs (~352 regs of f16
// pairs). h/x broadcasts via tiny LDS buffers; within a single wave the
// compiler's lgkmcnt waits give ordering for free.
__launch_bounds__(64, 1)
__global__ void lstm2_wave_kernel(const float* __restrict__ x1,
                                  const float* __restrict__ x2,
                                  const float* __restrict__ Wih1,
                                  const float* __restrict__ Whh1,
                                  const float* __restrict__ bih1,
                                  const float* __restrict__ bhh1,
                                  const float* __restrict__ Wih2,
                                  const float* __restrict__ Whh2,
                                  const float* __restrict__ bih2,
                                  const float* __restrict__ bhh2,
                                  float* __restrict__ out)
{
  __shared__ u32 s_x[2][32];   // x_t as f16 pairs, double buffered
  __shared__ u32 s_h1[32];     // h1 as f16 pairs (64 values)
  __shared__ u32 s_h2[16];     // h2 as f16 pairs (32 values)

  const int lane = threadIdx.x;          // 0..63
  const int bid = blockIdx.x;            // 0..511
  const int which = bid >> 8;            // 0 -> x1, 1 -> x2
  const int row = bid & 255;
  const float* __restrict__ xg = (which ? x2 : x1) + row * (TT * 64) + lane;

  // ---- one-time: weights -> VGPRs as f16 k-pairs ----
  u32 wih1r[4][32];   // layer-1 input weights, 4 gates of unit `lane`
  u32 whh1r[4][32];   // layer-1 recurrent
  u32 wih2r[2][32];   // layer-2 input, gates lane and lane+64
  u32 whh2r[2][16];   // layer-2 recurrent
  float b1r[4], b2r[2];

  #pragma unroll
  for (int g = 0; g < 4; ++g) {
    const int gate = lane + g * 64;
    const float* wr = Wih1 + gate * 64;
    #pragma unroll
    for (int kp = 0; kp < 32; ++kp) {
      const float2 w = *(const float2*)(wr + 2 * kp);
      wih1r[g][kp] = packh2(w.x, w.y);
    }
    const float* wh = Whh1 + gate * 64;
    #pragma unroll
    for (int kp = 0; kp < 32; ++kp) {
      const float2 w = *(const float2*)(wh + 2 * kp);
      whh1r[g][kp] = packh2(w.x, w.y);
    }
    b1r[g] = bih1[gate] + bhh1[gate];
  }
  #pragma unroll
  for (int g = 0; g < 2; ++g) {
    const int gate = lane + g * 64;      // l and l+64
    const float* wr = Wih2 + gate * 64;
    #pragma unroll
    for (int kp = 0; kp < 32; ++kp) {
      const float2 w = *(const float2*)(wr + 2 * kp);
      wih2r[g][kp] = packh2(w.x, w.y);
    }
    const float* wh = Whh2 + gate * 32;
    #pragma unroll
    for (int kp = 0; kp < 16; ++kp) {
      const float2 w = *(const float2*)(wh + 2 * kp);
      whh2r[g][kp] = packh2(w.x, w.y);
    }
    b2r[g] = bih2[gate] + bhh2[gate];
  }

  // ---- init state ----
  if (lane < 32) { s_h1[lane] = 0u; s_h2[lane & 15] = 0u; }
  ((f16*)s_h1)[lane] = (f16)0.f;               // all 64 h1 slots
  ((f16*)s_x[0])[lane] = (f16)xg[0];           // x_0
  float c1 = 0.f, c2 = 0.f;
  // prefetch x_1 (distance-2 pipeline below)
  float xpre = (TT > 1) ? xg[64] : 0.f;

  #pragma unroll 2
  for (int t = 0; t < TT; ++t) {
    const int cur = t & 1, nxt = cur ^ 1;

    // issue x prefetch for t+2 (consumed next iteration)
    float xpre2 = 0.f;
    if (t + 2 < TT) xpre2 = xg[(t + 2) * 64];

    // ---- layer-1 gates: x part (x_t from LDS buf cur) ----
    float a0 = b1r[0], a1 = b1r[1], a2 = b1r[2], a3 = b1r[3];
    #pragma unroll
    for (int q = 0; q < 8; ++q) {
      const uint4 xv = *(const uint4*)(&s_x[cur][4 * q]);
      a0 = fdot2f(wih1r[0][4*q+0], xv.x, a0);
      a1 = fdot2f(wih1r[1][4*q+0], xv.x, a1);
      a2 = fdot2f(wih1r[2][4*q+0], xv.x, a2);
      a3 = fdot2f(wih1r[3][4*q+0], xv.x, a3);
      a0 = fdot2f(wih1r[0][4*q+1], xv.y, a0);
      a1 = fdot2f(wih1r[1][4*q+1], xv.y, a1);
      a2 = fdot2f(wih1r[2][4*q+1], xv.y, a2);
      a3 = fdot2f(wih1r[3][4*q+1], xv.y, a3);
      a0 = fdot2f(wih1r[0][4*q+2], xv.z, a0);
      a1 = fdot2f(wih1r[1][4*q+2], xv.z, a1);
      a2 = fdot2f(wih1r[2][4*q+2], xv.z, a2);
      a3 = fdot2f(wih1r[3][4*q+2], xv.z, a3);
      a0 = fdot2f(wih1r[0][4*q+3], xv.w, a0);
      a1 = fdot2f(wih1r[1][4*q+3], xv.w, a1);
      a2 = fdot2f(wih1r[2][4*q+3], xv.w, a2);
      a3 = fdot2f(wih1r[3][4*q+3], xv.w, a3);
    }
    // ---- layer-1 gates: h part (h1_{t-1} from LDS) ----
    #pragma unroll
    for (int q = 0; q < 8; ++q) {
      const uint4 hv = *(const uint4*)(&s_h1[4 * q]);
      a0 = fdot2f(whh1r[0][4*q+0], hv.x, a0);
      a1 = fdot2f(whh1r[1][4*q+0], hv.x, a1);
      a2 = fdot2f(whh1r[2][4*q+0], hv.x, a2);
      a3 = fdot2f(whh1r[3][4*q+0], hv.x, a3);
      a0 = fdot2f(whh1r[0][4*q+1], hv.y, a0);
      a1 = fdot2f(whh1r[1][4*q+1], hv.y, a1);
      a2 = fdot2f(whh1r[2][4*q+1], hv.y, a2);
      a3 = fdot2f(whh1r[3][4*q+1], hv.y, a3);
      a0 = fdot2f(whh1r[0][4*q+2], hv.z, a0);
      a1 = fdot2f(whh1r[1][4*q+2], hv.z, a1);
      a2 = fdot2f(whh1r[2][4*q+2], hv.z, a2);
      a3 = fdot2f(whh1r[3][4*q+2], hv.z, a3);
      a0 = fdot2f(whh1r[0][4*q+3], hv.w, a0);
      a1 = fdot2f(whh1r[1][4*q+3], hv.w, a1);
      a2 = fdot2f(whh1r[2][4*q+3], hv.w, a2);
      a3 = fdot2f(whh1r[3][4*q+3], hv.w, a3);
    }

    // ---- layer-1 cell update (lane-local!) ----
    const float i1 = sigm(a0), f1 = sigm(a1), g1 = tanh_(a2), o1 = sigm(a3);
    c1 = f1 * c1 + i1 * g1;
    const float h1v = o1 * tanh_(c1);

    // publish h1_t; commit x_{t+1}
    ((f16*)s_h1)[lane] = (f16)h1v;
    ((f16*)s_x[nxt])[lane] = (f16)xpre;
    xpre = xpre2;

    // ---- layer-2 gates: lane l computes gates l and l+64 ----
    float b0 = b2r[0], b1_ = b2r[1];
    #pragma unroll
    for (int q = 0; q < 8; ++q) {
      const uint4 hv = *(const uint4*)(&s_h1[4 * q]);   // fresh h1_t
      b0  = fdot2f(wih2r[0][4*q+0], hv.x, b0);
      b1_ = fdot2f(wih2r[1][4*q+0], hv.x, b1_);
      b0  = fdot2f(wih2r[0][4*q+1], hv.y, b0);
      b1_ = fdot2f(wih2r[1][4*q+1], hv.y, b1_);
      b0  = fdot2f(wih2r[0][4*q+2], hv.z, b0);
      b1_ = fdot2f(wih2r[1][4*q+2], hv.z, b1_);
      b0  = fdot2f(wih2r[0][4*q+3], hv.w, b0);
      b1_ = fdot2f(wih2r[1][4*q+3], hv.w, b1_);
    }
    #pragma unroll
    for (int q = 0; q < 4; ++q) {
      const uint4 hv = *(const uint4*)(&s_h2[4 * q]);   // h2_{t-1}
      b0  = fdot2f(whh2r[0][4*q+0], hv.x, b0);
      b1_ = fdot2f(whh2r[1][4*q+0], hv.x, b1_);
      b0  = fdot2f(whh2r[0][4*q+1], hv.y, b0);
      b1_ = fdot2f(whh2r[1][4*q+1], hv.y, b1_);
      b0  = fdot2f(whh2r[0][4*q+2], hv.z, b0);
      b1_ = fdot2f(whh2r[1][4*q+2], hv.z, b1_);
      b0  = fdot2f(whh2r[0][4*q+3], hv.w, b0);
      b1_ = fdot2f(whh2r[1][4*q+3], hv.w, b1_);
    }

    // exchange with partner lane (l ^ 32): lane l<32 has (i,g), l>=32 has (f,o)
    const float p0 = __shfl_xor(b0, 32, 64);
    const float p1 = __shfl_xor(b1_, 32, 64);
    const bool lo = lane < 32;
    const float gi = lo ? b0  : p0;
    const float gf = lo ? p0  : b0;
    const float gg = lo ? b1_ : p1;
    const float go = lo ? p1  : b1_;

    const float i2 = sigm(gi), f2 = sigm(gf), g2v = tanh_(gg), o2 = sigm(go);
    c2 = f2 * c2 + i2 * g2v;
    const float h2v = o2 * tanh_(c2);
    if (lo) ((f16*)s_h2)[lane] = (f16)h2v;
    if (t == TT - 1 && lo) out[which * 8192 + row * 32 + lane] = h2v;
  }
}

extern "C" void kernel_launch(void* const* d_in, const int* in_sizes, int n_in,
                              void* d_out, int out_size, void* d_ws, size_t ws_size,
                              hipStream_t stream) {
  const float* x1   = (const float*)d_in[0];
  const float* x2   = (const float*)d_in[1];
  const float* Wih1 = (const float*)d_in[2];
  const float* Whh1 = (const float*)d_in[3];
  const float* bih1 = (const float*)d_in[4];
  const float* bhh1 = (const float*)d_in[5];
  const float* Wih2 = (const float*)d_in[6];
  const float* Whh2 = (const float*)d_in[7];
  const float* bih2 = (const float*)d_in[8];
  const float* bhh2 = (const float*)d_in[9];
  float* out = (float*)d_out;

  lstm2_wave_kernel<<<dim3(512), dim3(64), 0, stream>>>(
      x1, x2, Wih1, Whh1, bih1, bhh1, Wih2, Whh2, bih2, bhh2, out);
}

// Round 3
// 1787.278 us; speedup vs baseline: 2.4691x; 2.4691x over previous
//
#include <hip/hip_runtime.h>

#define TT 2048

typedef _Float16 f16;
typedef _Float16 f16x2 __attribute__((ext_vector_type(2)));
typedef unsigned int u32;

static __device__ __forceinline__ float fdot2f(u32 a, u32 b, float c) {
  return __builtin_amdgcn_fdot2(__builtin_bit_cast(f16x2, a),
                                __builtin_bit_cast(f16x2, b), c, false);
}
static __device__ __forceinline__ u32 packh2(float a, float b) {
  f16x2 v; v[0] = (f16)a; v[1] = (f16)b;
  return __builtin_bit_cast(u32, v);
}
static __device__ __forceinline__ float sigm(float x) {
  return 1.f / (1.f + __expf(-x));
}
static __device__ __forceinline__ float tanh_(float x) {
  x = fminf(15.f, fmaxf(-15.f, x));
  const float e = __expf(2.f * x);
  return (e - 1.f) / (e + 1.f);
}

// One block = one batch row = 3 specialized waves (192 threads):
//   waveP (wid 0): Wih1 in regs (128 u32). Computes pre1[t+2] into LDS ring.
//   wave0 (wid 1): Whh1 in regs (128 u32). The serial chain: h1_t from
//                  pre1[t] + Whh1 h1_{t-1}. Lane u owns unit u (4 gates).
//   wave1 (wid 2): Wih2+Whh2 packed in the SAME w[4][32] array (96 u32).
//                  Runs one step behind: computes h2_{t-1} from h1_{t-1}.
// One uniform __syncthreads per iteration; every cross-wave LDS buffer has
// >=1 barrier between producer write and consumer read (ring depth 4 for
// pre, double buffer for h1). Weight regs per wave <=128 -> no spills.
__launch_bounds__(192, 2)
__global__ void lstm2_pc_kernel(const float* __restrict__ x1,
                                const float* __restrict__ x2,
                                const float* __restrict__ Wih1,
                                const float* __restrict__ Whh1,
                                const float* __restrict__ bih1,
                                const float* __restrict__ bhh1,
                                const float* __restrict__ Wih2,
                                const float* __restrict__ Whh2,
                                const float* __restrict__ bih2,
                                const float* __restrict__ bhh2,
                                float* __restrict__ out)
{
  __shared__ u32 s_x[32];          // x_{t+2} as f16 pairs (waveP-local use)
  __shared__ u32 s_h1[2][32];      // h1 double buffer, f16 pairs
  __shared__ u32 s_h2[16];         // h2, f16 pairs (wave1-private)
  __shared__ float s_pre[4][256];  // pre1 ring, f32

  const int tid = threadIdx.x;
  const int lane = tid & 63;
  const int wid = tid >> 6;
  const int bid = blockIdx.x;
  const int which = bid >> 8;      // 0 -> x1, 1 -> x2
  const int row = bid & 255;
  const float* __restrict__ xg = (which ? x2 : x1) + row * (TT * 64) + lane;

  u32 w[4][32];
  float bias[4] = {0.f, 0.f, 0.f, 0.f};

  if (wid == 0) {
    // producer: Wih1 rows for gates lane + 64g
    #pragma unroll
    for (int g = 0; g < 4; ++g) {
      const float* src = Wih1 + (lane + 64 * g) * 64;
      #pragma unroll
      for (int kp = 0; kp < 32; ++kp) {
        const float2 v = *(const float2*)(src + 2 * kp);
        w[g][kp] = packh2(v.x, v.y);
      }
      bias[g] = bih1[lane + 64 * g] + bhh1[lane + 64 * g];
    }
  } else if (wid == 1) {
    // layer-1 recurrent: Whh1 rows for gates lane + 64g
    #pragma unroll
    for (int g = 0; g < 4; ++g) {
      const float* src = Whh1 + (lane + 64 * g) * 64;
      #pragma unroll
      for (int kp = 0; kp < 32; ++kp) {
        const float2 v = *(const float2*)(src + 2 * kp);
        w[g][kp] = packh2(v.x, v.y);
      }
    }
    if (lane < 32) s_h1[1][lane] = 0u;   // h1[-1] lives in slot (-1)&1 == 1
  } else {
    // layer-2: Wih2 gates lane, lane+64 -> w[0],w[1]; Whh2 -> w[2],w[3][0..15]
    #pragma unroll
    for (int g = 0; g < 2; ++g) {
      const float* src = Wih2 + (lane + 64 * g) * 64;
      #pragma unroll
      for (int kp = 0; kp < 32; ++kp) {
        const float2 v = *(const float2*)(src + 2 * kp);
        w[g][kp] = packh2(v.x, v.y);
      }
      const float* s2 = Whh2 + (lane + 64 * g) * 32;
      #pragma unroll
      for (int kp = 0; kp < 16; ++kp) {
        const float2 v = *(const float2*)(s2 + 2 * kp);
        w[2 + g][kp] = packh2(v.x, v.y);
      }
      #pragma unroll
      for (int kp = 16; kp < 32; ++kp) w[2 + g][kp] = 0u;
      bias[g] = bih2[lane + 64 * g] + bhh2[lane + 64 * g];
    }
    if (lane < 16) s_h2[lane] = 0u;
  }

  float c1 = 0.f, c2 = 0.f;
  float xA = 0.f, xB = 0.f;

  // ---- prologue: waveP fills pre[0], pre[1]; primes x pipeline ----
  if (wid == 0) {
    #pragma unroll
    for (int p = 0; p < 2; ++p) {
      ((f16*)s_x)[lane] = (f16)xg[p * 64];
      // same-wave write->read through s_x (validated pattern from R2's h1)
      float a0 = bias[0], a1 = bias[1], a2 = bias[2], a3 = bias[3];
      #pragma unroll
      for (int q = 0; q < 8; ++q) {
        const uint4 xv = *(const uint4*)&s_x[4 * q];
        a0 = fdot2f(w[0][4*q+0], xv.x, a0); a1 = fdot2f(w[1][4*q+0], xv.x, a1);
        a2 = fdot2f(w[2][4*q+0], xv.x, a2); a3 = fdot2f(w[3][4*q+0], xv.x, a3);
        a0 = fdot2f(w[0][4*q+1], xv.y, a0); a1 = fdot2f(w[1][4*q+1], xv.y, a1);
        a2 = fdot2f(w[2][4*q+1], xv.y, a2); a3 = fdot2f(w[3][4*q+1], xv.y, a3);
        a0 = fdot2f(w[0][4*q+2], xv.z, a0); a1 = fdot2f(w[1][4*q+2], xv.z, a1);
        a2 = fdot2f(w[2][4*q+2], xv.z, a2); a3 = fdot2f(w[3][4*q+2], xv.z, a3);
        a0 = fdot2f(w[0][4*q+3], xv.w, a0); a1 = fdot2f(w[1][4*q+3], xv.w, a1);
        a2 = fdot2f(w[2][4*q+3], xv.w, a2); a3 = fdot2f(w[3][4*q+3], xv.w, a3);
      }
      s_pre[p][lane]       = a0;
      s_pre[p][lane + 64]  = a1;
      s_pre[p][lane + 128] = a2;
      s_pre[p][lane + 192] = a3;
    }
    xA = xg[2 * 64];   // x[2]
    xB = xg[3 * 64];   // x[3]
  }
  __syncthreads();

  #pragma unroll 1
  for (int i = 0; i <= TT; ++i) {
    if (wid == 0) {
      // produce pre1[i+2]
      if (i + 2 < TT) {
        ((f16*)s_x)[lane] = (f16)xA;       // xA == x[i+2]
        xA = xB;
        xB = (i + 4 < TT) ? xg[(i + 4) * 64] : 0.f;
        float a0 = bias[0], a1 = bias[1], a2 = bias[2], a3 = bias[3];
        #pragma unroll
        for (int q = 0; q < 8; ++q) {
          const uint4 xv = *(const uint4*)&s_x[4 * q];
          a0 = fdot2f(w[0][4*q+0], xv.x, a0); a1 = fdot2f(w[1][4*q+0], xv.x, a1);
          a2 = fdot2f(w[2][4*q+0], xv.x, a2); a3 = fdot2f(w[3][4*q+0], xv.x, a3);
          a0 = fdot2f(w[0][4*q+1], xv.y, a0); a1 = fdot2f(w[1][4*q+1], xv.y, a1);
          a2 = fdot2f(w[2][4*q+1], xv.y, a2); a3 = fdot2f(w[3][4*q+1], xv.y, a3);
          a0 = fdot2f(w[0][4*q+2], xv.z, a0); a1 = fdot2f(w[1][4*q+2], xv.z, a1);
          a2 = fdot2f(w[2][4*q+2], xv.z, a2); a3 = fdot2f(w[3][4*q+2], xv.z, a3);
          a0 = fdot2f(w[0][4*q+3], xv.w, a0); a1 = fdot2f(w[1][4*q+3], xv.w, a1);
          a2 = fdot2f(w[2][4*q+3], xv.w, a2); a3 = fdot2f(w[3][4*q+3], xv.w, a3);
        }
        const int sl = (i + 2) & 3;
        s_pre[sl][lane]       = a0;
        s_pre[sl][lane + 64]  = a1;
        s_pre[sl][lane + 128] = a2;
        s_pre[sl][lane + 192] = a3;
      }
    } else if (wid == 1) {
      // layer-1 step i: h1_i = LSTM1(pre[i], h1_{i-1}); lane-local update
      if (i < TT) {
        const float* pr = s_pre[i & 3];
        float a0 = pr[lane], a1 = pr[lane + 64];
        float a2 = pr[lane + 128], a3 = pr[lane + 192];
        const u32* hp = s_h1[(i + 1) & 1];          // h1[i-1]
        #pragma unroll
        for (int q = 0; q < 8; ++q) {
          const uint4 hv = *(const uint4*)&hp[4 * q];
          a0 = fdot2f(w[0][4*q+0], hv.x, a0); a1 = fdot2f(w[1][4*q+0], hv.x, a1);
          a2 = fdot2f(w[2][4*q+0], hv.x, a2); a3 = fdot2f(w[3][4*q+0], hv.x, a3);
          a0 = fdot2f(w[0][4*q+1], hv.y, a0); a1 = fdot2f(w[1][4*q+1], hv.y, a1);
          a2 = fdot2f(w[2][4*q+1], hv.y, a2); a3 = fdot2f(w[3][4*q+1], hv.y, a3);
          a0 = fdot2f(w[0][4*q+2], hv.z, a0); a1 = fdot2f(w[1][4*q+2], hv.z, a1);
          a2 = fdot2f(w[2][4*q+2], hv.z, a2); a3 = fdot2f(w[3][4*q+2], hv.z, a3);
          a0 = fdot2f(w[0][4*q+3], hv.w, a0); a1 = fdot2f(w[1][4*q+3], hv.w, a1);
          a2 = fdot2f(w[2][4*q+3], hv.w, a2); a3 = fdot2f(w[3][4*q+3], hv.w, a3);
        }
        const float i1 = sigm(a0), f1 = sigm(a1), g1 = tanh_(a2), o1 = sigm(a3);
        c1 = f1 * c1 + i1 * g1;
        const float h1v = o1 * tanh_(c1);
        ((f16*)s_h1[i & 1])[lane] = (f16)h1v;
      }
    } else {
      // layer-2, one step behind: t = i-1
      if (i > 0) {
        const int t = i - 1;
        float b0 = bias[0], b1_ = bias[1];
        const u32* hp = s_h1[t & 1];                // h1[t]
        #pragma unroll
        for (int q = 0; q < 8; ++q) {
          const uint4 hv = *(const uint4*)&hp[4 * q];
          b0 = fdot2f(w[0][4*q+0], hv.x, b0); b1_ = fdot2f(w[1][4*q+0], hv.x, b1_);
          b0 = fdot2f(w[0][4*q+1], hv.y, b0); b1_ = fdot2f(w[1][4*q+1], hv.y, b1_);
          b0 = fdot2f(w[0][4*q+2], hv.z, b0); b1_ = fdot2f(w[1][4*q+2], hv.z, b1_);
          b0 = fdot2f(w[0][4*q+3], hv.w, b0); b1_ = fdot2f(w[1][4*q+3], hv.w, b1_);
        }
        #pragma unroll
        for (int q = 0; q < 4; ++q) {
          const uint4 hv = *(const uint4*)&s_h2[4 * q];   // h2[t-1]
          b0 = fdot2f(w[2][4*q+0], hv.x, b0); b1_ = fdot2f(w[3][4*q+0], hv.x, b1_);
          b0 = fdot2f(w[2][4*q+1], hv.y, b0); b1_ = fdot2f(w[3][4*q+1], hv.y, b1_);
          b0 = fdot2f(w[2][4*q+2], hv.z, b0); b1_ = fdot2f(w[3][4*q+2], hv.z, b1_);
          b0 = fdot2f(w[2][4*q+3], hv.w, b0); b1_ = fdot2f(w[3][4*q+3], hv.w, b1_);
        }
        const float p0 = __shfl_xor(b0, 32, 64);
        const float p1 = __shfl_xor(b1_, 32, 64);
        const bool lo = lane < 32;
        const float gi = lo ? b0  : p0;
        const float gf = lo ? p0  : b0;
        const float gg = lo ? b1_ : p1;
        const float go = lo ? p1  : b1_;
        const float i2 = sigm(gi), f2 = sigm(gf), g2v = tanh_(gg), o2 = sigm(go);
        c2 = f2 * c2 + i2 * g2v;
        const float h2v = o2 * tanh_(c2);
        if (lo) ((f16*)s_h2)[lane] = (f16)h2v;
        if (t == TT - 1 && lo) out[which * 8192 + row * 32 + lane] = h2v;
      }
    }
    __syncthreads();
  }
}

extern "C" void kernel_launch(void* const* d_in, const int* in_sizes, int n_in,
                              void* d_out, int out_size, void* d_ws, size_t ws_size,
                              hipStream_t stream) {
  const float* x1   = (const float*)d_in[0];
  const float* x2   = (const float*)d_in[1];
  const float* Wih1 = (const float*)d_in[2];
  const float* Whh1 = (const float*)d_in[3];
  const float* bih1 = (const float*)d_in[4];
  const float* bhh1 = (const float*)d_in[5];
  const float* Wih2 = (const float*)d_in[6];
  const float* Whh2 = (const float*)d_in[7];
  const float* bih2 = (const float*)d_in[8];
  const float* bhh2 = (const float*)d_in[9];
  float* out = (float*)d_out;

  lstm2_pc_kernel<<<dim3(512), dim3(192), 0, stream>>>(
      x1, x2, Wih1, Whh1, bih1, bhh1, Wih2, Whh2, bih2, bhh2, out);
}

// Round 4
// 1745.249 us; speedup vs baseline: 2.5286x; 1.0241x over previous
//
#include <hip/hip_runtime.h>

#define TT 2048

typedef _Float16 f16;
typedef _Float16 f16x2 __attribute__((ext_vector_type(2)));
typedef unsigned int u32;

static __device__ __forceinline__ float fdot2f(u32 a, u32 b, float c) {
  return __builtin_amdgcn_fdot2(__builtin_bit_cast(f16x2, a),
                                __builtin_bit_cast(f16x2, b), c, false);
}
static __device__ __forceinline__ u32 packh2(float a, float b) {
  f16x2 v; v[0] = (f16)a; v[1] = (f16)b;
  return __builtin_bit_cast(u32, v);
}
static __device__ __forceinline__ float sigm(float x) {
  return 1.f / (1.f + __expf(-x));
}
static __device__ __forceinline__ float tanh_(float x) {
  x = fminf(15.f, fmaxf(-15.f, x));
  const float e = __expf(2.f * x);
  return (e - 1.f) / (e + 1.f);
}

// 3 specialized waves per row (as R3). Key change vs R3: waveP's global x
// loads are batched 8 timesteps per superstep into 8 NAMED registers
// (static indices), committed to an 8-slot LDS ring at superstep start.
// __syncthreads drains vmcnt(0) every iteration (compiler emits
// s_waitcnt vmcnt(0) before s_barrier), so per-iteration prefetches eat a
// full HBM latency at EVERY barrier; batching 8 loads amortizes that
// drain to ~1/8 per iter.
__launch_bounds__(192, 2)
__global__ void lstm2_pc2_kernel(const float* __restrict__ x1,
                                 const float* __restrict__ x2,
                                 const float* __restrict__ Wih1,
                                 const float* __restrict__ Whh1,
                                 const float* __restrict__ bih1,
                                 const float* __restrict__ bhh1,
                                 const float* __restrict__ Wih2,
                                 const float* __restrict__ Whh2,
                                 const float* __restrict__ bih2,
                                 const float* __restrict__ bhh2,
                                 float* __restrict__ out)
{
  __shared__ u32 s_xbig[8][32];    // x ring: slot t&7 holds x[t] as f16 pairs
  __shared__ u32 s_h1[2][32];      // h1 double buffer, f16 pairs
  __shared__ u32 s_h2[16];         // h2, f16 pairs (wave2-private)
  __shared__ float s_pre[4][256];  // pre1 ring, f32

  const int tid = threadIdx.x;
  const int lane = tid & 63;
  const int wid = tid >> 6;
  const int bid = blockIdx.x;
  const int which = bid >> 8;      // 0 -> x1, 1 -> x2
  const int row = bid & 255;
  const float* __restrict__ xg = (which ? x2 : x1) + row * (TT * 64) + lane;

  u32 w[4][32];
  float bias[4] = {0.f, 0.f, 0.f, 0.f};

  if (wid == 0) {
    #pragma unroll
    for (int g = 0; g < 4; ++g) {
      const float* src = Wih1 + (lane + 64 * g) * 64;
      #pragma unroll
      for (int kp = 0; kp < 32; ++kp) {
        const float2 v = *(const float2*)(src + 2 * kp);
        w[g][kp] = packh2(v.x, v.y);
      }
      bias[g] = bih1[lane + 64 * g] + bhh1[lane + 64 * g];
    }
  } else if (wid == 1) {
    #pragma unroll
    for (int g = 0; g < 4; ++g) {
      const float* src = Whh1 + (lane + 64 * g) * 64;
      #pragma unroll
      for (int kp = 0; kp < 32; ++kp) {
        const float2 v = *(const float2*)(src + 2 * kp);
        w[g][kp] = packh2(v.x, v.y);
      }
    }
    if (lane < 32) s_h1[1][lane] = 0u;   // h1[-1] in slot (-1)&1 == 1
  } else {
    #pragma unroll
    for (int g = 0; g < 2; ++g) {
      const float* src = Wih2 + (lane + 64 * g) * 64;
      #pragma unroll
      for (int kp = 0; kp < 32; ++kp) {
        const float2 v = *(const float2*)(src + 2 * kp);
        w[g][kp] = packh2(v.x, v.y);
      }
      const float* s2 = Whh2 + (lane + 64 * g) * 32;
      #pragma unroll
      for (int kp = 0; kp < 16; ++kp) {
        const float2 v = *(const float2*)(s2 + 2 * kp);
        w[2 + g][kp] = packh2(v.x, v.y);
      }
      #pragma unroll
      for (int kp = 16; kp < 32; ++kp) w[2 + g][kp] = 0u;
      bias[g] = bih2[lane + 64 * g] + bhh2[lane + 64 * g];
    }
    if (lane < 16) s_h2[lane] = 0u;
  }

  float c1 = 0.f, c2 = 0.f;
  // 8 named prefetch registers (static indices only -> stay in VGPRs)
  float xr0 = 0.f, xr1 = 0.f, xr2 = 0.f, xr3 = 0.f;
  float xr4 = 0.f, xr5 = 0.f, xr6 = 0.f, xr7 = 0.f;

  // ---- prologue (waveP): x[0],x[1] -> slots 0,1; pre[0],pre[1]; prime xr ----
  if (wid == 0) {
    ((f16*)s_xbig[0])[lane] = (f16)xg[0];
    ((f16*)s_xbig[1])[lane] = (f16)xg[64];
    #pragma unroll
    for (int p = 0; p < 2; ++p) {
      float a0 = bias[0], a1 = bias[1], a2 = bias[2], a3 = bias[3];
      const u32* xp = s_xbig[p];
      #pragma unroll
      for (int q = 0; q < 8; ++q) {
        const uint4 xv = *(const uint4*)&xp[4 * q];
        a0 = fdot2f(w[0][4*q+0], xv.x, a0); a1 = fdot2f(w[1][4*q+0], xv.x, a1);
        a2 = fdot2f(w[2][4*q+0], xv.x, a2); a3 = fdot2f(w[3][4*q+0], xv.x, a3);
        a0 = fdot2f(w[0][4*q+1], xv.y, a0); a1 = fdot2f(w[1][4*q+1], xv.y, a1);
        a2 = fdot2f(w[2][4*q+1], xv.y, a2); a3 = fdot2f(w[3][4*q+1], xv.y, a3);
        a0 = fdot2f(w[0][4*q+2], xv.z, a0); a1 = fdot2f(w[1][4*q+2], xv.z, a1);
        a2 = fdot2f(w[2][4*q+2], xv.z, a2); a3 = fdot2f(w[3][4*q+2], xv.z, a3);
        a0 = fdot2f(w[0][4*q+3], xv.w, a0); a1 = fdot2f(w[1][4*q+3], xv.w, a1);
        a2 = fdot2f(w[2][4*q+3], xv.w, a2); a3 = fdot2f(w[3][4*q+3], xv.w, a3);
      }
      s_pre[p][lane]       = a0;
      s_pre[p][lane + 64]  = a1;
      s_pre[p][lane + 128] = a2;
      s_pre[p][lane + 192] = a3;
    }
    // prime xr = x[2..9] (committed at iter 0)
    xr0 = xg[2 * 64]; xr1 = xg[3 * 64]; xr2 = xg[4 * 64]; xr3 = xg[5 * 64];
    xr4 = xg[6 * 64]; xr5 = xg[7 * 64]; xr6 = xg[8 * 64]; xr7 = xg[9 * 64];
  }
  __syncthreads();

  #pragma unroll 1
  for (int i = 0; i <= TT; ++i) {
    if (wid == 0) {
      if ((i & 7) == 0) {
        // commit xr (= x[i+2 .. i+9]) to ring slots (t & 7)
        ((f16*)s_xbig[(i + 2) & 7])[lane] = (f16)xr0;
        ((f16*)s_xbig[(i + 3) & 7])[lane] = (f16)xr1;
        ((f16*)s_xbig[(i + 4) & 7])[lane] = (f16)xr2;
        ((f16*)s_xbig[(i + 5) & 7])[lane] = (f16)xr3;
        ((f16*)s_xbig[(i + 6) & 7])[lane] = (f16)xr4;
        ((f16*)s_xbig[(i + 7) & 7])[lane] = (f16)xr5;
        ((f16*)s_xbig[(i + 8) & 7])[lane] = (f16)xr6;
        ((f16*)s_xbig[(i + 9) & 7])[lane] = (f16)xr7;
        // issue next batch x[i+10 .. i+17] (clamped; clamped values unused)
        const int tm = TT - 1;
        xr0 = xg[(i + 10 < TT ? i + 10 : tm) * 64];
        xr1 = xg[(i + 11 < TT ? i + 11 : tm) * 64];
        xr2 = xg[(i + 12 < TT ? i + 12 : tm) * 64];
        xr3 = xg[(i + 13 < TT ? i + 13 : tm) * 64];
        xr4 = xg[(i + 14 < TT ? i + 14 : tm) * 64];
        xr5 = xg[(i + 15 < TT ? i + 15 : tm) * 64];
        xr6 = xg[(i + 16 < TT ? i + 16 : tm) * 64];
        xr7 = xg[(i + 17 < TT ? i + 17 : tm) * 64];
      }
      if (i + 2 < TT) {
        float a0 = bias[0], a1 = bias[1], a2 = bias[2], a3 = bias[3];
        const u32* xp = s_xbig[(i + 2) & 7];
        #pragma unroll
        for (int q = 0; q < 8; ++q) {
          const uint4 xv = *(const uint4*)&xp[4 * q];
          a0 = fdot2f(w[0][4*q+0], xv.x, a0); a1 = fdot2f(w[1][4*q+0], xv.x, a1);
          a2 = fdot2f(w[2][4*q+0], xv.x, a2); a3 = fdot2f(w[3][4*q+0], xv.x, a3);
          a0 = fdot2f(w[0][4*q+1], xv.y, a0); a1 = fdot2f(w[1][4*q+1], xv.y, a1);
          a2 = fdot2f(w[2][4*q+1], xv.y, a2); a3 = fdot2f(w[3][4*q+1], xv.y, a3);
          a0 = fdot2f(w[0][4*q+2], xv.z, a0); a1 = fdot2f(w[1][4*q+2], xv.z, a1);
          a2 = fdot2f(w[2][4*q+2], xv.z, a2); a3 = fdot2f(w[3][4*q+2], xv.z, a3);
          a0 = fdot2f(w[0][4*q+3], xv.w, a0); a1 = fdot2f(w[1][4*q+3], xv.w, a1);
          a2 = fdot2f(w[2][4*q+3], xv.w, a2); a3 = fdot2f(w[3][4*q+3], xv.w, a3);
        }
        const int sl = (i + 2) & 3;
        s_pre[sl][lane]       = a0;
        s_pre[sl][lane + 64]  = a1;
        s_pre[sl][lane + 128] = a2;
        s_pre[sl][lane + 192] = a3;
      }
    } else if (wid == 1) {
      // layer-1 step i: even/odd-split accumulators (8 chains of 16)
      if (i < TT) {
        const float* pr = s_pre[i & 3];
        float a0 = pr[lane], a1 = pr[lane + 64];
        float a2 = pr[lane + 128], a3 = pr[lane + 192];
        float e0 = 0.f, e1 = 0.f, e2 = 0.f, e3 = 0.f;
        const u32* hp = s_h1[(i + 1) & 1];          // h1[i-1]
        #pragma unroll
        for (int q = 0; q < 8; ++q) {
          const uint4 hv = *(const uint4*)&hp[4 * q];
          a0 = fdot2f(w[0][4*q+0], hv.x, a0); e0 = fdot2f(w[0][4*q+1], hv.y, e0);
          a1 = fdot2f(w[1][4*q+0], hv.x, a1); e1 = fdot2f(w[1][4*q+1], hv.y, e1);
          a2 = fdot2f(w[2][4*q+0], hv.x, a2); e2 = fdot2f(w[2][4*q+1], hv.y, e2);
          a3 = fdot2f(w[3][4*q+0], hv.x, a3); e3 = fdot2f(w[3][4*q+1], hv.y, e3);
          a0 = fdot2f(w[0][4*q+2], hv.z, a0); e0 = fdot2f(w[0][4*q+3], hv.w, e0);
          a1 = fdot2f(w[1][4*q+2], hv.z, a1); e1 = fdot2f(w[1][4*q+3], hv.w, e1);
          a2 = fdot2f(w[2][4*q+2], hv.z, a2); e2 = fdot2f(w[2][4*q+3], hv.w, e2);
          a3 = fdot2f(w[3][4*q+2], hv.z, a3); e3 = fdot2f(w[3][4*q+3], hv.w, e3);
        }
        a0 += e0; a1 += e1; a2 += e2; a3 += e3;
        const float i1 = sigm(a0), f1 = sigm(a1), g1 = tanh_(a2), o1 = sigm(a3);
        c1 = f1 * c1 + i1 * g1;
        const float h1v = o1 * tanh_(c1);
        ((f16*)s_h1[i & 1])[lane] = (f16)h1v;
      }
    } else {
      // layer-2, one step behind: t = i-1
      if (i > 0) {
        const int t = i - 1;
        float b0 = bias[0], b1_ = bias[1];
        float e0 = 0.f, e1 = 0.f;
        const u32* hp = s_h1[t & 1];                // h1[t]
        #pragma unroll
        for (int q = 0; q < 8; ++q) {
          const uint4 hv = *(const uint4*)&hp[4 * q];
          b0 = fdot2f(w[0][4*q+0], hv.x, b0); e0 = fdot2f(w[0][4*q+1], hv.y, e0);
          b1_ = fdot2f(w[1][4*q+0], hv.x, b1_); e1 = fdot2f(w[1][4*q+1], hv.y, e1);
          b0 = fdot2f(w[0][4*q+2], hv.z, b0); e0 = fdot2f(w[0][4*q+3], hv.w, e0);
          b1_ = fdot2f(w[1][4*q+2], hv.z, b1_); e1 = fdot2f(w[1][4*q+3], hv.w, e1);
        }
        #pragma unroll
        for (int q = 0; q < 4; ++q) {
          const uint4 hv = *(const uint4*)&s_h2[4 * q];   // h2[t-1]
          b0 = fdot2f(w[2][4*q+0], hv.x, b0); e0 = fdot2f(w[2][4*q+1], hv.y, e0);
          b1_ = fdot2f(w[3][4*q+0], hv.x, b1_); e1 = fdot2f(w[3][4*q+1], hv.y, e1);
          b0 = fdot2f(w[2][4*q+2], hv.z, b0); e0 = fdot2f(w[2][4*q+3], hv.w, e0);
          b1_ = fdot2f(w[3][4*q+2], hv.z, b1_); e1 = fdot2f(w[3][4*q+3], hv.w, e1);
        }
        b0 += e0; b1_ += e1;
        const float p0 = __shfl_xor(b0, 32, 64);
        const float p1 = __shfl_xor(b1_, 32, 64);
        const bool lo = lane < 32;
        const float gi = lo ? b0  : p0;
        const float gf = lo ? p0  : b0;
        const float gg = lo ? b1_ : p1;
        const float go = lo ? p1  : b1_;
        const float i2 = sigm(gi), f2 = sigm(gf), g2v = tanh_(gg), o2 = sigm(go);
        c2 = f2 * c2 + i2 * g2v;
        const float h2v = o2 * tanh_(c2);
        if (lo) ((f16*)s_h2)[lane] = (f16)h2v;
        if (t == TT - 1 && lo) out[which * 8192 + row * 32 + lane] = h2v;
      }
    }
    __syncthreads();
  }
}

extern "C" void kernel_launch(void* const* d_in, const int* in_sizes, int n_in,
                              void* d_out, int out_size, void* d_ws, size_t ws_size,
                              hipStream_t stream) {
  const float* x1   = (const float*)d_in[0];
  const float* x2   = (const float*)d_in[1];
  const float* Wih1 = (const float*)d_in[2];
  const float* Whh1 = (const float*)d_in[3];
  const float* bih1 = (const float*)d_in[4];
  const float* bhh1 = (const float*)d_in[5];
  const float* Wih2 = (const float*)d_in[6];
  const float* Whh2 = (const float*)d_in[7];
  const float* bih2 = (const float*)d_in[8];
  const float* bhh2 = (const float*)d_in[9];
  float* out = (float*)d_out;

  lstm2_pc2_kernel<<<dim3(512), dim3(192), 0, stream>>>(
      x1, x2, Wih1, Whh1, bih1, bhh1, Wih2, Whh2, bih2, bhh2, out);
}